// Round 4
// baseline (377.791 us; speedup 1.0000x reference)
//
#include <hip/hip_runtime.h>

// ---------------------------------------------------------------------------
// LabelSimilarity: match[b,l] = max(-1, max_{s,v} cos(embed[s,b,:], label[l,v,:]))
// S=256 B=128 D=768 ; L=200 V=8 ; out [128,200] fp32
//
// R4: (a) B fragments load straight from global (L1/L2-hot: each 196 KB
// B n-tile is reused by 256 s-blocks) — halves LDS traffic and the
// vmcnt(0) barrier-drain volume. (b) BK=64: 16 KB A tile, 32 MFMA per
// barrier-pair, 24 barriers instead of 48. A-tile swizzle: slot = q^(row&7)
// inside each row's 128 B (conflict-free per 8-lane phase; R2/R3 validated
// the scheme). Epilogue/reduce pipeline unchanged from R3.
// ---------------------------------------------------------------------------

typedef __bf16 bf16x8 __attribute__((ext_vector_type(8)));
typedef float  f32x4  __attribute__((ext_vector_type(4)));

#define GLD16(gp, lp) __builtin_amdgcn_global_load_lds(                        \
    (__attribute__((address_space(1))) void*)(gp),                             \
    (__attribute__((address_space(3))) void*)(lp), 16, 0, 0)

__device__ __forceinline__ unsigned short f32_to_bf16_rne(float x) {
  unsigned u = __float_as_uint(x);
  u += 0x7fffu + ((u >> 16) & 1u);
  return (unsigned short)(u >> 16);
}

// One wave per row: L2-normalize a 768-elem fp32 row -> bf16. Rows >= nsrc are
// zero pad rows (for N padding 1600->1664).
__global__ void __launch_bounds__(256) normalize_rows(
    const float* __restrict__ src, unsigned short* __restrict__ dst,
    int nsrc, int ndst) {
  int row  = blockIdx.x * 4 + (threadIdx.x >> 6);
  int lane = threadIdx.x & 63;
  if (row >= ndst) return;
  ushort4* drow = (ushort4*)(dst + (size_t)row * 768);
  if (row >= nsrc) {
    ushort4 z; z.x = z.y = z.z = z.w = 0;
#pragma unroll
    for (int t = 0; t < 3; ++t) drow[lane + 64 * t] = z;
    return;
  }
  const float4* srow = (const float4*)(src + (size_t)row * 768);
  float4 v[3];
  float ss = 0.f;
#pragma unroll
  for (int t = 0; t < 3; ++t) {
    v[t] = srow[lane + 64 * t];
    ss += v[t].x * v[t].x + v[t].y * v[t].y + v[t].z * v[t].z + v[t].w * v[t].w;
  }
#pragma unroll
  for (int off = 1; off < 64; off <<= 1) ss += __shfl_xor(ss, off);
  float rinv = rsqrtf(fmaxf(ss, 1e-12f));
#pragma unroll
  for (int t = 0; t < 3; ++t) {
    ushort4 h;
    h.x = f32_to_bf16_rne(v[t].x * rinv);
    h.y = f32_to_bf16_rne(v[t].y * rinv);
    h.z = f32_to_bf16_rne(v[t].z * rinv);
    h.w = f32_to_bf16_rne(v[t].w * rinv);
    drow[lane + 64 * t] = h;
  }
}

// GEMM + per-block max tile. Block = (n-tile bx in [0,13), s = by in [0,256)).
__global__ void __launch_bounds__(256) gemm_store_kernel(
    const unsigned short* __restrict__ Ap,   // [32768][768] bf16 (normalized)
    const unsigned short* __restrict__ Bp,   // [1664][768]  bf16 (normalized)
    float* __restrict__ scratch) {
  __shared__ char smem[16384];   // A tile [128 rows][64 k] bf16, swizzled

  const int t    = threadIdx.x;
  const int lane = t & 63;
  const int w    = t >> 6;             // wave 0..3
  const int s    = blockIdx.y;
  const int n0   = blockIdx.x * 128;

  // --- A staging: 4 GLD16 calls/iter; call p, thread t -> slot p*256+t.
  //     slot -> row = slot>>3, q_s = slot&7; holds global chunk q_s^(row&7).
  const int rowp = t >> 3;             // 0..31 (within 32-row group)
  const int qs   = t & 7;
  const char* gA = (const char*)(Ap + (size_t)(s * 128) * 768);
  const char* ga[4];
#pragma unroll
  for (int p = 0; p < 4; ++p)
    ga[p] = gA + (size_t)(p * 32 + rowp) * 1536 + (qs ^ (rowp & 7)) * 16;
  char* lp[4];
#pragma unroll
  for (int p = 0; p < 4; ++p) lp[p] = smem + p * 4096 + w * 1024;

  // --- wave tile: 2x2 waves, each 64x64 = 4x4 MFMA tiles of 16x16 ---
  const int wm  = (w >> 1) * 64;
  const int wn  = (w & 1) * 64;
  const int r16 = lane & 15;
  const int g   = lane >> 4;           // k-chunk within 32-k half

  // A fragment byte offsets in smem (row stride 128 B, slot = q ^ (r16&7)):
  const int slot0 = g ^ (r16 & 7);          // c=0: q = g
  const int a0 = (wm + r16) * 128 + slot0 * 16;
  const int a1 = (wm + r16) * 128 + (slot0 ^ 4) * 16;   // c=1: q = 4+g

  // B fragment global base pointers (bytes): row n0+wn+j*16+r16, k-offset g*16
  const char* gBb = (const char*)Bp;
  const char* bbase[4];
#pragma unroll
  for (int j = 0; j < 4; ++j)
    bbase[j] = gBb + (size_t)(n0 + wn + j * 16 + r16) * 1536 + g * 16;

  f32x4 acc[4][4];
#pragma unroll
  for (int i = 0; i < 4; ++i)
#pragma unroll
    for (int j = 0; j < 4; ++j)
      acc[i][j] = (f32x4){0.f, 0.f, 0.f, 0.f};

  for (int kk = 0; kk < 12; ++kk) {    // K = 768 = 12 * 64
    GLD16(ga[0], lp[0]); GLD16(ga[1], lp[1]);
    GLD16(ga[2], lp[2]); GLD16(ga[3], lp[3]);
#pragma unroll
    for (int p = 0; p < 4; ++p) ga[p] += 128;
    // B fragments for both 32-k halves, straight from global (L1/L2-hot)
    bf16x8 bf0[4], bf1[4];
#pragma unroll
    for (int j = 0; j < 4; ++j) {
      bf0[j] = *(const bf16x8*)(bbase[j]);
      bf1[j] = *(const bf16x8*)(bbase[j] + 64);
      bbase[j] += 128;
    }
    __syncthreads();                   // drains vmcnt(0): A tile + B frags ready
    bf16x8 af[4];
#pragma unroll
    for (int i = 0; i < 4; ++i)
      af[i] = *(const bf16x8*)(smem + a0 + i * 2048);
#pragma unroll
    for (int i = 0; i < 4; ++i)
#pragma unroll
      for (int j = 0; j < 4; ++j)
        acc[i][j] = __builtin_amdgcn_mfma_f32_16x16x32_bf16(
            af[i], bf0[j], acc[i][j], 0, 0, 0);
#pragma unroll
    for (int i = 0; i < 4; ++i)
      af[i] = *(const bf16x8*)(smem + a1 + i * 2048);
#pragma unroll
    for (int i = 0; i < 4; ++i)
#pragma unroll
      for (int j = 0; j < 4; ++j)
        acc[i][j] = __builtin_amdgcn_mfma_f32_16x16x32_bf16(
            af[i], bf1[j], acc[i][j], 0, 0, 0);
    __syncthreads();                   // protect A tile before next stage
  }

  // epilogue: acc is cos. C/D: col=lane&15, row=(lane>>4)*4+r.
  // max over v (col groups of 8) via shuffle; compact via LDS (stride 17),
  // then coalesced float4 stores to the block's private scratch tile.
  float* red = (float*)smem;           // [128][17] floats = 8704 B
  const int rowg  = lane >> 4;
  const int lbit  = (lane >> 3) & 1;
  const bool writer = (lane & 7) == 0;
  __syncthreads();                     // A-tile reads done (last iter)
#pragma unroll
  for (int i = 0; i < 4; ++i) {
#pragma unroll
    for (int j = 0; j < 4; ++j) {
#pragma unroll
      for (int r = 0; r < 4; ++r) {
        float vv = acc[i][j][r];
        vv = fmaxf(vv, __shfl_xor(vv, 1));
        vv = fmaxf(vv, __shfl_xor(vv, 2));
        vv = fmaxf(vv, __shfl_xor(vv, 4));
        if (writer) {
          int b  = wm + i * 16 + rowg * 4 + r;
          int ll = (wn >> 3) + j * 2 + lbit;
          red[b * 17 + ll] = vv;
        }
      }
    }
  }
  __syncthreads();
  {
    const int b  = t >> 1;
    const int l8 = (t & 1) * 8;
    float4 p0, p1;
    p0.x = red[b * 17 + l8 + 0]; p0.y = red[b * 17 + l8 + 1];
    p0.z = red[b * 17 + l8 + 2]; p0.w = red[b * 17 + l8 + 3];
    p1.x = red[b * 17 + l8 + 4]; p1.y = red[b * 17 + l8 + 5];
    p1.z = red[b * 17 + l8 + 6]; p1.w = red[b * 17 + l8 + 7];
    float4* gg = (float4*)(scratch + ((size_t)(blockIdx.x * 256 + s)) * 2048 + t * 8);
    gg[0] = p0; gg[1] = p1;
  }
}

// reduce1: block (bx, sg) folds s in [sg*8, sg*8+8) -> partial[bx][sg][2048]
__global__ void __launch_bounds__(256) reduce1_kernel(
    const float* __restrict__ scratch, float* __restrict__ partial) {
  const int t  = threadIdx.x;
  const int bx = blockIdx.x;
  const int sg = blockIdx.y;
  const float* base = scratch + ((size_t)(bx * 256 + sg * 8)) * 2048 + t * 8;
  float4 m0 = ((const float4*)base)[0];
  float4 m1 = ((const float4*)base)[1];
  for (int ss = 1; ss < 8; ++ss) {
    const float4* p = (const float4*)(base + (size_t)ss * 2048);
    float4 a = p[0], b = p[1];
    m0.x = fmaxf(m0.x, a.x); m0.y = fmaxf(m0.y, a.y);
    m0.z = fmaxf(m0.z, a.z); m0.w = fmaxf(m0.w, a.w);
    m1.x = fmaxf(m1.x, b.x); m1.y = fmaxf(m1.y, b.y);
    m1.z = fmaxf(m1.z, b.z); m1.w = fmaxf(m1.w, b.w);
  }
  float4* o = (float4*)(partial + ((size_t)(bx * 32 + sg)) * 2048 + t * 8);
  o[0] = m0; o[1] = m1;
}

// reduce2: out[b][l] = max(-1, max over 32 partials)
__global__ void __launch_bounds__(256) reduce2_kernel(
    const float* __restrict__ partial, float* __restrict__ out) {
  int idx = blockIdx.x * 256 + threadIdx.x;   // 0 .. 26623
  if (idx >= 13 * 2048) return;
  int bx = idx >> 11;
  int e  = idx & 2047;
  int b  = e >> 4;
  int ll = e & 15;
  int l  = bx * 16 + ll;
  if (l >= 200) return;
  float m = -1.0f;
  const float* p = partial + (size_t)(bx * 32) * 2048 + e;
  for (int c = 0; c < 32; ++c) m = fmaxf(m, p[(size_t)c * 2048]);
  out[b * 200 + l] = m;
}

// Brute-force fp32 fallback (only if ws_size is too small): one block per (b,l).
__global__ void __launch_bounds__(256) fallback_kernel(
    const float* __restrict__ embed, const float* __restrict__ label,
    float* __restrict__ out) {
  int b = blockIdx.x, l = blockIdx.y, t = threadIdx.x;
  float m = -1.0f;
  for (int p = t; p < 2048; p += 256) {
    int s = p >> 3, v = p & 7;
    const float* e = embed + (size_t)(s * 128 + b) * 768;
    const float* q = label + (size_t)(l * 8 + v) * 768;
    float dot = 0.f, ne = 0.f, nl = 0.f;
    for (int d = 0; d < 768; ++d) {
      float x = e[d], y = q[d];
      dot += x * y; ne += x * x; nl += y * y;
    }
    m = fmaxf(m, dot / fmaxf(sqrtf(ne) * sqrtf(nl), 1e-8f));
  }
  for (int off = 1; off < 64; off <<= 1) m = fmaxf(m, __shfl_xor(m, off));
  __shared__ float wmax[4];
  if ((t & 63) == 0) wmax[t >> 6] = m;
  __syncthreads();
  if (t == 0)
    out[b * 200 + l] = fmaxf(fmaxf(wmax[0], wmax[1]), fmaxf(wmax[2], wmax[3]));
}

extern "C" void kernel_launch(void* const* d_in, const int* in_sizes, int n_in,
                              void* d_out, int out_size, void* d_ws, size_t ws_size,
                              hipStream_t stream) {
  const float* embed = (const float*)d_in[0];   // [256,128,768]
  const float* label = (const float*)d_in[1];   // [200,8,768]
  float* out = (float*)d_out;                   // [128,200]

  const size_t szA = (size_t)32768 * 768 * 2;        // 50,331,648
  const size_t szB = (size_t)1664 * 768 * 2;         //  2,555,904
  const size_t szS = (size_t)13 * 256 * 2048 * 4;    // 27,262,976
  const size_t szP = (size_t)13 * 32 * 2048 * 4;     //  3,407,872

  if (ws_size < szA + szB + szS + szP) {
    dim3 g(128, 200);
    fallback_kernel<<<g, 256, 0, stream>>>(embed, label, out);
    return;
  }

  unsigned short* Ap = (unsigned short*)d_ws;
  unsigned short* Bp = (unsigned short*)((char*)d_ws + szA);
  float* scratch     = (float*)((char*)d_ws + szA + szB);
  float* partial     = (float*)((char*)d_ws + szA + szB + szS);

  normalize_rows<<<32768 / 4, 256, 0, stream>>>(embed, Ap, 32768, 32768);
  normalize_rows<<<1664 / 4, 256, 0, stream>>>(label, Bp, 1600, 1664);
  dim3 g(13, 256);  // 13 n-tiles x 256 s = 3328 blocks
  gemm_store_kernel<<<g, 256, 0, stream>>>(Ap, Bp, scratch);
  dim3 r1(13, 32);
  reduce1_kernel<<<r1, 256, 0, stream>>>(scratch, partial);
  reduce2_kernel<<<104, 256, 0, stream>>>(partial, out);
}

// Round 5
// 354.537 us; speedup vs baseline: 1.0656x; 1.0656x over previous
//
#include <hip/hip_runtime.h>

// ---------------------------------------------------------------------------
// LabelSimilarity: match[b,l] = max(-1, max_{s,v} cos(embed[s,b,:], label[l,v,:]))
// S=256 B=128 D=768 ; L=200 V=8 ; out [128,200] fp32
//
// R5: revert to R3 data path (A+B staged via global_load_lds, XOR-swizzled,
// 0 conflicts). BK=64 via TWO full buffer sets (32 KB LDS): 8 GLD16 + one
// barrier-pair per 32 MFMA -> barrier drains halved vs R3. R4 lesson baked
// in: anything drained at the barrier must be global_load_lds (per-lane
// global B fragments cost VGPRs + exposed latency -> 233 us regression).
// reduce1+reduce2 fused into one kernel.
// ---------------------------------------------------------------------------

typedef __bf16 bf16x8 __attribute__((ext_vector_type(8)));
typedef float  f32x4  __attribute__((ext_vector_type(4)));

#define GLD16(gp, lp) __builtin_amdgcn_global_load_lds(                        \
    (__attribute__((address_space(1))) void*)(gp),                             \
    (__attribute__((address_space(3))) void*)(lp), 16, 0, 0)

__device__ __forceinline__ unsigned short f32_to_bf16_rne(float x) {
  unsigned u = __float_as_uint(x);
  u += 0x7fffu + ((u >> 16) & 1u);
  return (unsigned short)(u >> 16);
}

// One wave per row: L2-normalize a 768-elem fp32 row -> bf16. Rows >= nsrc are
// zero pad rows (for N padding 1600->1664).
__global__ void __launch_bounds__(256) normalize_rows(
    const float* __restrict__ src, unsigned short* __restrict__ dst,
    int nsrc, int ndst) {
  int row  = blockIdx.x * 4 + (threadIdx.x >> 6);
  int lane = threadIdx.x & 63;
  if (row >= ndst) return;
  ushort4* drow = (ushort4*)(dst + (size_t)row * 768);
  if (row >= nsrc) {
    ushort4 z; z.x = z.y = z.z = z.w = 0;
#pragma unroll
    for (int t = 0; t < 3; ++t) drow[lane + 64 * t] = z;
    return;
  }
  const float4* srow = (const float4*)(src + (size_t)row * 768);
  float4 v[3];
  float ss = 0.f;
#pragma unroll
  for (int t = 0; t < 3; ++t) {
    v[t] = srow[lane + 64 * t];
    ss += v[t].x * v[t].x + v[t].y * v[t].y + v[t].z * v[t].z + v[t].w * v[t].w;
  }
#pragma unroll
  for (int off = 1; off < 64; off <<= 1) ss += __shfl_xor(ss, off);
  float rinv = rsqrtf(fmaxf(ss, 1e-12f));
#pragma unroll
  for (int t = 0; t < 3; ++t) {
    ushort4 h;
    h.x = f32_to_bf16_rne(v[t].x * rinv);
    h.y = f32_to_bf16_rne(v[t].y * rinv);
    h.z = f32_to_bf16_rne(v[t].z * rinv);
    h.w = f32_to_bf16_rne(v[t].w * rinv);
    drow[lane + 64 * t] = h;
  }
}

// GEMM + per-block max tile. Block = (n-tile bx in [0,13), s = by in [0,256)).
// Writes scratch[(bx*256+s)*2048 + b*16 + ll].
__global__ void __launch_bounds__(256) gemm_store_kernel(
    const unsigned short* __restrict__ Ap,   // [32768][768] bf16 (normalized)
    const unsigned short* __restrict__ Bp,   // [1664][768]  bf16 (normalized)
    float* __restrict__ scratch) {
  __shared__ char smem[32768];
  // buffer sets: As0 | Bs0 | As1 | Bs1, each [128 rows][32 k] bf16, swizzled
  char* const As0 = smem;
  char* const Bs0 = smem + 8192;
  char* const As1 = smem + 16384;
  char* const Bs1 = smem + 24576;

  const int t    = threadIdx.x;
  const int lane = t & 63;
  const int w    = t >> 6;             // wave 0..3
  const int s    = blockIdx.y;
  const int n0   = blockIdx.x * 128;

  // staging (per 8KB tile): LDS slot == t (16B). slot (row=t>>2, cs=t&3)
  // holds global chunk cg = cs ^ ((row>>1)&3) (stays inside row's 64B line).
  const int srow = t >> 2;
  const int cg   = (t & 3) ^ ((t >> 3) & 3);
  const char* gA = (const char*)(Ap + (size_t)(s * 128) * 768);
  const char* gB = (const char*)(Bp + (size_t)n0 * 768);
  const char* ga0 = gA + srow * 1536 + cg * 16;          // rows 0..63
  const char* ga1 = ga0 + 64 * 1536;                     // rows 64..127
  const char* gb0 = gB + srow * 1536 + cg * 16;
  const char* gb1 = gb0 + 64 * 1536;
  char* const lA0_0 = As0 + w * 1024;
  char* const lA1_0 = As0 + 4096 + w * 1024;
  char* const lB0_0 = Bs0 + w * 1024;
  char* const lB1_0 = Bs0 + 4096 + w * 1024;
  char* const lA0_1 = As1 + w * 1024;
  char* const lA1_1 = As1 + 4096 + w * 1024;
  char* const lB0_1 = Bs1 + w * 1024;
  char* const lB1_1 = Bs1 + 4096 + w * 1024;

  // wave tile: 2x2 waves, each 64x64 = 4x4 MFMA tiles of 16x16
  const int wm  = (w >> 1) * 64;
  const int wn  = (w & 1) * 64;
  const int r16 = lane & 15;
  const int swz  = (((lane >> 4) ^ ((r16 >> 1) & 3)) * 16);   // bytes
  const int aoffB = (wm + r16) * 64 + swz;
  const int boffB = (wn + r16) * 64 + swz;

  f32x4 acc[4][4];
#pragma unroll
  for (int i = 0; i < 4; ++i)
#pragma unroll
    for (int j = 0; j < 4; ++j)
      acc[i][j] = (f32x4){0.f, 0.f, 0.f, 0.f};

  for (int kk = 0; kk < 12; ++kk) {    // K = 768 = 12 * 64
    // stage k-chunk 0 into set 0, k-chunk 1 into set 1 (8 x GLD16)
    GLD16(ga0,      lA0_0); GLD16(ga1,      lA1_0);
    GLD16(gb0,      lB0_0); GLD16(gb1,      lB1_0);
    GLD16(ga0 + 64, lA0_1); GLD16(ga1 + 64, lA1_1);
    GLD16(gb0 + 64, lB0_1); GLD16(gb1 + 64, lB1_1);
    ga0 += 128; ga1 += 128; gb0 += 128; gb1 += 128;
    __syncthreads();                   // drains vmcnt(0): both sets ready
    bf16x8 af[4], bfr[4];
#pragma unroll
    for (int i = 0; i < 4; ++i) af[i]  = *(const bf16x8*)(As0 + aoffB + i * 1024);
#pragma unroll
    for (int j = 0; j < 4; ++j) bfr[j] = *(const bf16x8*)(Bs0 + boffB + j * 1024);
#pragma unroll
    for (int i = 0; i < 4; ++i)
#pragma unroll
      for (int j = 0; j < 4; ++j)
        acc[i][j] = __builtin_amdgcn_mfma_f32_16x16x32_bf16(
            af[i], bfr[j], acc[i][j], 0, 0, 0);
#pragma unroll
    for (int i = 0; i < 4; ++i) af[i]  = *(const bf16x8*)(As1 + aoffB + i * 1024);
#pragma unroll
    for (int j = 0; j < 4; ++j) bfr[j] = *(const bf16x8*)(Bs1 + boffB + j * 1024);
#pragma unroll
    for (int i = 0; i < 4; ++i)
#pragma unroll
      for (int j = 0; j < 4; ++j)
        acc[i][j] = __builtin_amdgcn_mfma_f32_16x16x32_bf16(
            af[i], bfr[j], acc[i][j], 0, 0, 0);
    __syncthreads();                   // protect LDS before next stage
  }

  // epilogue: acc is cos. C/D: col=lane&15, row=(lane>>4)*4+r.
  // max over v (col groups of 8) via shuffle; compact via LDS (stride 17),
  // then coalesced float4 stores to the block's private scratch tile.
  float* red = (float*)smem;           // [128][17] floats = 8704 B
  const int rowg  = lane >> 4;
  const int lbit  = (lane >> 3) & 1;
  const bool writer = (lane & 7) == 0;
#pragma unroll
  for (int i = 0; i < 4; ++i) {
#pragma unroll
    for (int j = 0; j < 4; ++j) {
#pragma unroll
      for (int r = 0; r < 4; ++r) {
        float vv = acc[i][j][r];
        vv = fmaxf(vv, __shfl_xor(vv, 1));
        vv = fmaxf(vv, __shfl_xor(vv, 2));
        vv = fmaxf(vv, __shfl_xor(vv, 4));
        if (writer) {
          int b  = wm + i * 16 + rowg * 4 + r;
          int ll = (wn >> 3) + j * 2 + lbit;
          red[b * 17 + ll] = vv;
        }
      }
    }
  }
  __syncthreads();
  {
    const int b  = t >> 1;
    const int l8 = (t & 1) * 8;
    float4 p0, p1;
    p0.x = red[b * 17 + l8 + 0]; p0.y = red[b * 17 + l8 + 1];
    p0.z = red[b * 17 + l8 + 2]; p0.w = red[b * 17 + l8 + 3];
    p1.x = red[b * 17 + l8 + 4]; p1.y = red[b * 17 + l8 + 5];
    p1.z = red[b * 17 + l8 + 6]; p1.w = red[b * 17 + l8 + 7];
    float4* gg = (float4*)(scratch + ((size_t)(blockIdx.x * 256 + s)) * 2048 + t * 8);
    gg[0] = p0; gg[1] = p1;
  }
}

// fused reduce: thread (bx, e) folds all 256 s-tiles -> out[b][l]
__global__ void __launch_bounds__(256) reduce_kernel(
    const float* __restrict__ scratch, float* __restrict__ out) {
  int idx = blockIdx.x * 256 + threadIdx.x;   // 0 .. 26623
  int bx = idx >> 11;
  int e  = idx & 2047;
  int b  = e >> 4;
  int ll = e & 15;
  int l  = bx * 16 + ll;
  if (l >= 200) return;
  const float* p = scratch + (size_t)(bx * 256) * 2048 + e;
  float m = -1.0f;
#pragma unroll 8
  for (int s = 0; s < 256; ++s) m = fmaxf(m, p[(size_t)s * 2048]);
  out[b * 200 + l] = m;
}

// Brute-force fp32 fallback (only if ws_size is too small): one block per (b,l).
__global__ void __launch_bounds__(256) fallback_kernel(
    const float* __restrict__ embed, const float* __restrict__ label,
    float* __restrict__ out) {
  int b = blockIdx.x, l = blockIdx.y, t = threadIdx.x;
  float m = -1.0f;
  for (int p = t; p < 2048; p += 256) {
    int s = p >> 3, v = p & 7;
    const float* e = embed + (size_t)(s * 128 + b) * 768;
    const float* q = label + (size_t)(l * 8 + v) * 768;
    float dot = 0.f, ne = 0.f, nl = 0.f;
    for (int d = 0; d < 768; ++d) {
      float x = e[d], y = q[d];
      dot += x * y; ne += x * x; nl += y * y;
    }
    m = fmaxf(m, dot / fmaxf(sqrtf(ne) * sqrtf(nl), 1e-8f));
  }
  for (int off = 1; off < 64; off <<= 1) m = fmaxf(m, __shfl_xor(m, off));
  __shared__ float wmax[4];
  if ((t & 63) == 0) wmax[t >> 6] = m;
  __syncthreads();
  if (t == 0)
    out[b * 200 + l] = fmaxf(fmaxf(wmax[0], wmax[1]), fmaxf(wmax[2], wmax[3]));
}

extern "C" void kernel_launch(void* const* d_in, const int* in_sizes, int n_in,
                              void* d_out, int out_size, void* d_ws, size_t ws_size,
                              hipStream_t stream) {
  const float* embed = (const float*)d_in[0];   // [256,128,768]
  const float* label = (const float*)d_in[1];   // [200,8,768]
  float* out = (float*)d_out;                   // [128,200]

  const size_t szA = (size_t)32768 * 768 * 2;        // 50,331,648
  const size_t szB = (size_t)1664 * 768 * 2;         //  2,555,904
  const size_t szS = (size_t)13 * 256 * 2048 * 4;    // 27,262,976

  if (ws_size < szA + szB + szS) {
    dim3 g(128, 200);
    fallback_kernel<<<g, 256, 0, stream>>>(embed, label, out);
    return;
  }

  unsigned short* Ap = (unsigned short*)d_ws;
  unsigned short* Bp = (unsigned short*)((char*)d_ws + szA);
  float* scratch     = (float*)((char*)d_ws + szA + szB);

  normalize_rows<<<32768 / 4, 256, 0, stream>>>(embed, Ap, 32768, 32768);
  normalize_rows<<<1664 / 4, 256, 0, stream>>>(label, Bp, 1600, 1664);
  dim3 g(13, 256);  // 13 n-tiles x 256 s = 3328 blocks
  gemm_store_kernel<<<g, 256, 0, stream>>>(Ap, Bp, scratch);
  reduce_kernel<<<104, 256, 0, stream>>>(scratch, out);
}

// Round 6
// 293.817 us; speedup vs baseline: 1.2858x; 1.2067x over previous
//
#include <hip/hip_runtime.h>

// ---------------------------------------------------------------------------
// LabelSimilarity: match[b,l] = max(-1, max_{s,v} cos(embed[s,b,:], label[l,v,:]))
// S=256 B=128 D=768 ; L=200 V=8 ; out [128,200] fp32
//
// R6: R3 gemm data path (BK=32, 16 KB LDS, XOR-swizzled GLD16 staging,
// 0 bank conflicts — best at 154 us) + XCD-aware block clustering:
// the 13 n-tile blocks sharing one A-tile run near-simultaneously on ONE
// XCD's L2 (R3's grid spread them across all 8 -> 247 MB HBM fetch of a
// 53 MB input). R5 lesson: fewer barriers via bigger LDS loses to occupancy
// (BK=64/32KB: 166 us, occ 21%). Two-stage reduce (R3 layout).
// ---------------------------------------------------------------------------

typedef __bf16 bf16x8 __attribute__((ext_vector_type(8)));
typedef float  f32x4  __attribute__((ext_vector_type(4)));

#define GLD16(gp, lp) __builtin_amdgcn_global_load_lds(                        \
    (__attribute__((address_space(1))) void*)(gp),                             \
    (__attribute__((address_space(3))) void*)(lp), 16, 0, 0)

__device__ __forceinline__ unsigned short f32_to_bf16_rne(float x) {
  unsigned u = __float_as_uint(x);
  u += 0x7fffu + ((u >> 16) & 1u);
  return (unsigned short)(u >> 16);
}

// One wave per row: L2-normalize a 768-elem fp32 row -> bf16. Rows >= nsrc are
// zero pad rows (for N padding 1600->1664).
__global__ void __launch_bounds__(256) normalize_rows(
    const float* __restrict__ src, unsigned short* __restrict__ dst,
    int nsrc, int ndst) {
  int row  = blockIdx.x * 4 + (threadIdx.x >> 6);
  int lane = threadIdx.x & 63;
  if (row >= ndst) return;
  ushort4* drow = (ushort4*)(dst + (size_t)row * 768);
  if (row >= nsrc) {
    ushort4 z; z.x = z.y = z.z = z.w = 0;
#pragma unroll
    for (int t = 0; t < 3; ++t) drow[lane + 64 * t] = z;
    return;
  }
  const float4* srow = (const float4*)(src + (size_t)row * 768);
  float4 v[3];
  float ss = 0.f;
#pragma unroll
  for (int t = 0; t < 3; ++t) {
    v[t] = srow[lane + 64 * t];
    ss += v[t].x * v[t].x + v[t].y * v[t].y + v[t].z * v[t].z + v[t].w * v[t].w;
  }
#pragma unroll
  for (int off = 1; off < 64; off <<= 1) ss += __shfl_xor(ss, off);
  float rinv = rsqrtf(fmaxf(ss, 1e-12f));
#pragma unroll
  for (int t = 0; t < 3; ++t) {
    ushort4 h;
    h.x = f32_to_bf16_rne(v[t].x * rinv);
    h.y = f32_to_bf16_rne(v[t].y * rinv);
    h.z = f32_to_bf16_rne(v[t].z * rinv);
    h.w = f32_to_bf16_rne(v[t].w * rinv);
    drow[lane + 64 * t] = h;
  }
}

// GEMM + per-block max tile. 1-D grid 3328; XCD-clustered (bx fast within
// an XCD so the 13 A-tile sharers hit one L2).
// Writes scratch[(bx*256+s)*2048 + b*16 + ll].
__global__ void __launch_bounds__(256) gemm_store_kernel(
    const unsigned short* __restrict__ Ap,   // [32768][768] bf16 (normalized)
    const unsigned short* __restrict__ Bp,   // [1664][768]  bf16 (normalized)
    float* __restrict__ scratch) {
  __shared__ char smem[16384];
  unsigned short* As = (unsigned short*)smem;          // [128][32] swizzled
  unsigned short* Bs = (unsigned short*)(smem + 8192); // [128][32] swizzled

  const int t    = threadIdx.x;
  const int lane = t & 63;
  const int w    = t >> 6;             // wave 0..3

  // XCD-aware decode: blk -> (bx, s). xcd = blk&7 (round-robin assumption;
  // contiguous assignment also co-locates the 13 sharers — span is 104 blks).
  const int blk = blockIdx.x;          // 0..3327
  const int xcd = blk & 7;
  const int idx = blk >> 3;            // 0..415
  const int bx  = idx % 13;            // fast -> A-sharers adjacent in time
  const int s   = xcd * 32 + idx / 13;
  const int n0  = bx * 128;

  // staging: LDS slot == t (16B). slot (row=t>>2, cs=t&3) holds global chunk
  // cg = cs ^ ((row>>1)&3) (swizzle stays inside the row's 64B line).
  const int srow = t >> 2;
  const int cg   = (t & 3) ^ ((t >> 3) & 3);
  const char* gA = (const char*)(Ap + (size_t)(s * 128) * 768);
  const char* gB = (const char*)(Bp + (size_t)n0 * 768);
  const char* ga0 = gA + srow * 1536 + cg * 16;          // rows 0..63
  const char* ga1 = ga0 + 64 * 1536;                     // rows 64..127
  const char* gb0 = gB + srow * 1536 + cg * 16;
  const char* gb1 = gb0 + 64 * 1536;
  char* lA0 = (char*)As + w * 1024;
  char* lA1 = (char*)As + 4096 + w * 1024;
  char* lB0 = (char*)Bs + w * 1024;
  char* lB1 = (char*)Bs + 4096 + w * 1024;

  // wave tile: 2x2 waves, each 64x64 = 4x4 MFMA tiles of 16x16
  const int wm  = (w >> 1) * 64;
  const int wn  = (w & 1) * 64;
  const int r16 = lane & 15;
  const int swz  = (((lane >> 4) ^ ((r16 >> 1) & 3)) * 16);   // bytes
  const int aoffB = (wm + r16) * 64 + swz;
  const int boffB = (wn + r16) * 64 + swz;

  f32x4 acc[4][4];
#pragma unroll
  for (int i = 0; i < 4; ++i)
#pragma unroll
    for (int j = 0; j < 4; ++j)
      acc[i][j] = (f32x4){0.f, 0.f, 0.f, 0.f};

  for (int kk = 0; kk < 24; ++kk) {    // K = 768 = 24 * 32
    GLD16(ga0, lA0); GLD16(ga1, lA1);
    GLD16(gb0, lB0); GLD16(gb1, lB1);
    ga0 += 64; ga1 += 64; gb0 += 64; gb1 += 64;
    __syncthreads();                   // drains vmcnt -> LDS tiles ready
    bf16x8 af[4], bfr[4];
#pragma unroll
    for (int i = 0; i < 4; ++i)
      af[i] = *(const bf16x8*)((const char*)As + aoffB + i * 1024);
#pragma unroll
    for (int j = 0; j < 4; ++j)
      bfr[j] = *(const bf16x8*)((const char*)Bs + boffB + j * 1024);
#pragma unroll
    for (int i = 0; i < 4; ++i)
#pragma unroll
      for (int j = 0; j < 4; ++j)
        acc[i][j] = __builtin_amdgcn_mfma_f32_16x16x32_bf16(
            af[i], bfr[j], acc[i][j], 0, 0, 0);
    __syncthreads();                   // protect LDS before next stage
  }

  // epilogue: acc is cos. C/D: col=lane&15, row=(lane>>4)*4+r.
  // max over v (col groups of 8) via shuffle; compact via LDS (stride 17),
  // then coalesced float4 stores to the block's private scratch tile.
  float* red = (float*)smem;           // [128][17] floats = 8704 B
  const int rowg  = lane >> 4;
  const int lbit  = (lane >> 3) & 1;
  const bool writer = (lane & 7) == 0;
#pragma unroll
  for (int i = 0; i < 4; ++i) {
#pragma unroll
    for (int j = 0; j < 4; ++j) {
#pragma unroll
      for (int r = 0; r < 4; ++r) {
        float vv = acc[i][j][r];
        vv = fmaxf(vv, __shfl_xor(vv, 1));
        vv = fmaxf(vv, __shfl_xor(vv, 2));
        vv = fmaxf(vv, __shfl_xor(vv, 4));
        if (writer) {
          int b  = wm + i * 16 + rowg * 4 + r;
          int ll = (wn >> 3) + j * 2 + lbit;
          red[b * 17 + ll] = vv;
        }
      }
    }
  }
  __syncthreads();
  {
    const int b  = t >> 1;
    const int l8 = (t & 1) * 8;
    float4 p0, p1;
    p0.x = red[b * 17 + l8 + 0]; p0.y = red[b * 17 + l8 + 1];
    p0.z = red[b * 17 + l8 + 2]; p0.w = red[b * 17 + l8 + 3];
    p1.x = red[b * 17 + l8 + 4]; p1.y = red[b * 17 + l8 + 5];
    p1.z = red[b * 17 + l8 + 6]; p1.w = red[b * 17 + l8 + 7];
    float4* gg = (float4*)(scratch + ((size_t)(bx * 256 + s)) * 2048 + t * 8);
    gg[0] = p0; gg[1] = p1;
  }
}

// reduce1: block (bx, sg) folds s in [sg*8, sg*8+8) -> partial[bx][sg][2048]
__global__ void __launch_bounds__(256) reduce1_kernel(
    const float* __restrict__ scratch, float* __restrict__ partial) {
  const int t  = threadIdx.x;
  const int bx = blockIdx.x;
  const int sg = blockIdx.y;
  const float* base = scratch + ((size_t)(bx * 256 + sg * 8)) * 2048 + t * 8;
  float4 m0 = ((const float4*)base)[0];
  float4 m1 = ((const float4*)base)[1];
  for (int ss = 1; ss < 8; ++ss) {
    const float4* p = (const float4*)(base + (size_t)ss * 2048);
    float4 a = p[0], b = p[1];
    m0.x = fmaxf(m0.x, a.x); m0.y = fmaxf(m0.y, a.y);
    m0.z = fmaxf(m0.z, a.z); m0.w = fmaxf(m0.w, a.w);
    m1.x = fmaxf(m1.x, b.x); m1.y = fmaxf(m1.y, b.y);
    m1.z = fmaxf(m1.z, b.z); m1.w = fmaxf(m1.w, b.w);
  }
  float4* o = (float4*)(partial + ((size_t)(bx * 32 + sg)) * 2048 + t * 8);
  o[0] = m0; o[1] = m1;
}

// reduce2: out[b][l] = max(-1, max over 32 partials)
__global__ void __launch_bounds__(256) reduce2_kernel(
    const float* __restrict__ partial, float* __restrict__ out) {
  int idx = blockIdx.x * 256 + threadIdx.x;   // 0 .. 26623
  if (idx >= 13 * 2048) return;
  int bx = idx >> 11;
  int e  = idx & 2047;
  int b  = e >> 4;
  int ll = e & 15;
  int l  = bx * 16 + ll;
  if (l >= 200) return;
  float m = -1.0f;
  const float* p = partial + (size_t)(bx * 32) * 2048 + e;
  for (int c = 0; c < 32; ++c) m = fmaxf(m, p[(size_t)c * 2048]);
  out[b * 200 + l] = m;
}

// Brute-force fp32 fallback (only if ws_size is too small): one block per (b,l).
__global__ void __launch_bounds__(256) fallback_kernel(
    const float* __restrict__ embed, const float* __restrict__ label,
    float* __restrict__ out) {
  int b = blockIdx.x, l = blockIdx.y, t = threadIdx.x;
  float m = -1.0f;
  for (int p = t; p < 2048; p += 256) {
    int s = p >> 3, v = p & 7;
    const float* e = embed + (size_t)(s * 128 + b) * 768;
    const float* q = label + (size_t)(l * 8 + v) * 768;
    float dot = 0.f, ne = 0.f, nl = 0.f;
    for (int d = 0; d < 768; ++d) {
      float x = e[d], y = q[d];
      dot += x * y; ne += x * x; nl += y * y;
    }
    m = fmaxf(m, dot / fmaxf(sqrtf(ne) * sqrtf(nl), 1e-8f));
  }
  for (int off = 1; off < 64; off <<= 1) m = fmaxf(m, __shfl_xor(m, off));
  __shared__ float wmax[4];
  if ((t & 63) == 0) wmax[t >> 6] = m;
  __syncthreads();
  if (t == 0)
    out[b * 200 + l] = fmaxf(fmaxf(wmax[0], wmax[1]), fmaxf(wmax[2], wmax[3]));
}

extern "C" void kernel_launch(void* const* d_in, const int* in_sizes, int n_in,
                              void* d_out, int out_size, void* d_ws, size_t ws_size,
                              hipStream_t stream) {
  const float* embed = (const float*)d_in[0];   // [256,128,768]
  const float* label = (const float*)d_in[1];   // [200,8,768]
  float* out = (float*)d_out;                   // [128,200]

  const size_t szA = (size_t)32768 * 768 * 2;        // 50,331,648
  const size_t szB = (size_t)1664 * 768 * 2;         //  2,555,904
  const size_t szS = (size_t)13 * 256 * 2048 * 4;    // 27,262,976
  const size_t szP = (size_t)13 * 32 * 2048 * 4;     //  3,407,872

  if (ws_size < szA + szB + szS + szP) {
    dim3 g(128, 200);
    fallback_kernel<<<g, 256, 0, stream>>>(embed, label, out);
    return;
  }

  unsigned short* Ap = (unsigned short*)d_ws;
  unsigned short* Bp = (unsigned short*)((char*)d_ws + szA);
  float* scratch     = (float*)((char*)d_ws + szA + szB);
  float* partial     = (float*)((char*)d_ws + szA + szB + szS);

  normalize_rows<<<32768 / 4, 256, 0, stream>>>(embed, Ap, 32768, 32768);
  normalize_rows<<<1664 / 4, 256, 0, stream>>>(label, Bp, 1600, 1664);
  gemm_store_kernel<<<3328, 256, 0, stream>>>(Ap, Bp, scratch);
  dim3 r1(13, 32);
  reduce1_kernel<<<r1, 256, 0, stream>>>(scratch, partial);
  reduce2_kernel<<<104, 256, 0, stream>>>(partial, out);
}

// Round 7
// 286.293 us; speedup vs baseline: 1.3196x; 1.0263x over previous
//
#include <hip/hip_runtime.h>

// ---------------------------------------------------------------------------
// LabelSimilarity: match[b,l] = max(-1, max_{s,v} cos(embed[s,b,:], label[l,v,:]))
// S=256 B=128 D=768 ; L=200 V=8 ; out [128,200] fp32
//
// R7: single-barrier software-pipelined K-loop. Double-buffered 16 KB tile
// sets (32 KB LDS); each iter: barrier (drains prefetch issued a FULL iter
// ago -> already landed), issue GLD16 for chunk k+1, compute chunk k.
// R5's dbuf failed because it staged-then-drained immediately (2 barriers,
// no lookahead). XCD clustering (R6, FETCH 247->58 MB) and XOR swizzle
// (R2, conflicts ~0) kept. Normalize launches merged into one kernel.
// ---------------------------------------------------------------------------

typedef __bf16 bf16x8 __attribute__((ext_vector_type(8)));
typedef float  f32x4  __attribute__((ext_vector_type(4)));

#define GLD16(gp, lp) __builtin_amdgcn_global_load_lds(                        \
    (__attribute__((address_space(1))) void*)(gp),                             \
    (__attribute__((address_space(3))) void*)(lp), 16, 0, 0)

__device__ __forceinline__ unsigned short f32_to_bf16_rne(float x) {
  unsigned u = __float_as_uint(x);
  u += 0x7fffu + ((u >> 16) & 1u);
  return (unsigned short)(u >> 16);
}

// One wave per row, both tensors in one launch:
// rows [0,32768) -> embed->Ap ; rows [32768, 32768+1664) -> label->Bp
// (label rows >= 1600 are zero pad).
__global__ void __launch_bounds__(256) normalize_all(
    const float* __restrict__ embed, const float* __restrict__ label,
    unsigned short* __restrict__ Ap, unsigned short* __restrict__ Bp) {
  int row  = blockIdx.x * 4 + (threadIdx.x >> 6);
  int lane = threadIdx.x & 63;
  const float* src;
  unsigned short* dstp;
  if (row < 32768) {
    src  = embed + (size_t)row * 768;
    dstp = Ap + (size_t)row * 768;
  } else {
    int lr = row - 32768;
    if (lr >= 1664) return;
    dstp = Bp + (size_t)lr * 768;
    if (lr >= 1600) {
      ushort4 z; z.x = z.y = z.z = z.w = 0;
      ushort4* drow = (ushort4*)dstp;
#pragma unroll
      for (int t = 0; t < 3; ++t) drow[lane + 64 * t] = z;
      return;
    }
    src = label + (size_t)lr * 768;
  }
  const float4* srow = (const float4*)src;
  ushort4* drow = (ushort4*)dstp;
  float4 v[3];
  float ss = 0.f;
#pragma unroll
  for (int t = 0; t < 3; ++t) {
    v[t] = srow[lane + 64 * t];
    ss += v[t].x * v[t].x + v[t].y * v[t].y + v[t].z * v[t].z + v[t].w * v[t].w;
  }
#pragma unroll
  for (int off = 1; off < 64; off <<= 1) ss += __shfl_xor(ss, off);
  float rinv = rsqrtf(fmaxf(ss, 1e-12f));
#pragma unroll
  for (int t = 0; t < 3; ++t) {
    ushort4 h;
    h.x = f32_to_bf16_rne(v[t].x * rinv);
    h.y = f32_to_bf16_rne(v[t].y * rinv);
    h.z = f32_to_bf16_rne(v[t].z * rinv);
    h.w = f32_to_bf16_rne(v[t].w * rinv);
    drow[lane + 64 * t] = h;
  }
}

// GEMM + per-block max tile. 1-D grid 3328; XCD-clustered.
// Writes scratch[(bx*256+s)*2048 + b*16 + ll].
__global__ void __launch_bounds__(256) gemm_store_kernel(
    const unsigned short* __restrict__ Ap,   // [32768][768] bf16 (normalized)
    const unsigned short* __restrict__ Bp,   // [1664][768]  bf16 (normalized)
    float* __restrict__ scratch) {
  __shared__ char smem[32768];   // set0: A[0,8K) B[8K,16K) ; set1: +16K

  const int t    = threadIdx.x;
  const int lane = t & 63;
  const int w    = t >> 6;             // wave 0..3

  // XCD-aware decode: blk -> (bx, s); the 13 A-tile sharers co-locate.
  const int blk = blockIdx.x;          // 0..3327
  const int xcd = blk & 7;
  const int idx = blk >> 3;            // 0..415
  const int bx  = idx % 13;
  const int s   = xcd * 32 + idx / 13;
  const int n0  = bx * 128;

  // staging: LDS slot == t (16B). slot (row=t>>2, cs=t&3) holds global chunk
  // cg = cs ^ ((row>>1)&3) (swizzle stays inside the row's 64B line).
  const int srow = t >> 2;
  const int cg   = (t & 3) ^ ((t >> 3) & 3);
  const char* gA = (const char*)(Ap + (size_t)(s * 128) * 768);
  const char* gB = (const char*)(Bp + (size_t)n0 * 768);
  const char* ga0 = gA + srow * 1536 + cg * 16;          // rows 0..63
  const char* ga1 = ga0 + 64 * 1536;                     // rows 64..127
  const char* gb0 = gB + srow * 1536 + cg * 16;
  const char* gb1 = gb0 + 64 * 1536;
  const int lA0 = w * 1024;            // offsets within a 16 KB set
  const int lA1 = 4096 + w * 1024;
  const int lB0 = 8192 + w * 1024;
  const int lB1 = 12288 + w * 1024;

  // wave tile: 2x2 waves, each 64x64 = 4x4 MFMA tiles of 16x16
  const int wm  = (w >> 1) * 64;
  const int wn  = (w & 1) * 64;
  const int r16 = lane & 15;
  const int swz  = (((lane >> 4) ^ ((r16 >> 1) & 3)) * 16);   // bytes
  const int aoffB = (wm + r16) * 64 + swz;          // within set's A half
  const int boffB = 8192 + (wn + r16) * 64 + swz;   // within set's B half

  f32x4 acc[4][4];
#pragma unroll
  for (int i = 0; i < 4; ++i)
#pragma unroll
    for (int j = 0; j < 4; ++j)
      acc[i][j] = (f32x4){0.f, 0.f, 0.f, 0.f};

  // prologue: stage chunk 0 into set 0
  GLD16(ga0, smem + lA0); GLD16(ga1, smem + lA1);
  GLD16(gb0, smem + lB0); GLD16(gb1, smem + lB1);
  ga0 += 64; ga1 += 64; gb0 += 64; gb1 += 64;

  for (int kk = 0; kk < 24; ++kk) {    // K = 768 = 24 * 32
    __syncthreads();                   // drains chunk-kk loads (issued 1 iter ago)
    char* const Sc = smem + (kk & 1) * 16384;        // compute set
    if (kk < 23) {                     // prefetch chunk kk+1 into other set
      char* const Sp = smem + ((kk + 1) & 1) * 16384;
      GLD16(ga0, Sp + lA0); GLD16(ga1, Sp + lA1);
      GLD16(gb0, Sp + lB0); GLD16(gb1, Sp + lB1);
      ga0 += 64; ga1 += 64; gb0 += 64; gb1 += 64;
    }
    bf16x8 af[4], bfr[4];
#pragma unroll
    for (int i = 0; i < 4; ++i)
      af[i] = *(const bf16x8*)(Sc + aoffB + i * 1024);
#pragma unroll
    for (int j = 0; j < 4; ++j)
      bfr[j] = *(const bf16x8*)(Sc + boffB + j * 1024);
#pragma unroll
    for (int i = 0; i < 4; ++i)
#pragma unroll
      for (int j = 0; j < 4; ++j)
        acc[i][j] = __builtin_amdgcn_mfma_f32_16x16x32_bf16(
            af[i], bfr[j], acc[i][j], 0, 0, 0);
  }
  __syncthreads();                     // all ds_reads done before smem reuse

  // epilogue: acc is cos. C/D: col=lane&15, row=(lane>>4)*4+r.
  // max over v (col groups of 8) via shuffle; compact via LDS (stride 17),
  // then coalesced float4 stores to the block's private scratch tile.
  float* red = (float*)smem;           // [128][17] floats = 8704 B
  const int rowg  = lane >> 4;
  const int lbit  = (lane >> 3) & 1;
  const bool writer = (lane & 7) == 0;
#pragma unroll
  for (int i = 0; i < 4; ++i) {
#pragma unroll
    for (int j = 0; j < 4; ++j) {
#pragma unroll
      for (int r = 0; r < 4; ++r) {
        float vv = acc[i][j][r];
        vv = fmaxf(vv, __shfl_xor(vv, 1));
        vv = fmaxf(vv, __shfl_xor(vv, 2));
        vv = fmaxf(vv, __shfl_xor(vv, 4));
        if (writer) {
          int b  = wm + i * 16 + rowg * 4 + r;
          int ll = (wn >> 3) + j * 2 + lbit;
          red[b * 17 + ll] = vv;
        }
      }
    }
  }
  __syncthreads();
  {
    const int b  = t >> 1;
    const int l8 = (t & 1) * 8;
    float4 p0, p1;
    p0.x = red[b * 17 + l8 + 0]; p0.y = red[b * 17 + l8 + 1];
    p0.z = red[b * 17 + l8 + 2]; p0.w = red[b * 17 + l8 + 3];
    p1.x = red[b * 17 + l8 + 4]; p1.y = red[b * 17 + l8 + 5];
    p1.z = red[b * 17 + l8 + 6]; p1.w = red[b * 17 + l8 + 7];
    float4* gg = (float4*)(scratch + ((size_t)(bx * 256 + s)) * 2048 + t * 8);
    gg[0] = p0; gg[1] = p1;
  }
}

// reduce1: block (bx, sg) folds s in [sg*8, sg*8+8) -> partial[bx][sg][2048]
__global__ void __launch_bounds__(256) reduce1_kernel(
    const float* __restrict__ scratch, float* __restrict__ partial) {
  const int t  = threadIdx.x;
  const int bx = blockIdx.x;
  const int sg = blockIdx.y;
  const float* base = scratch + ((size_t)(bx * 256 + sg * 8)) * 2048 + t * 8;
  float4 m0 = ((const float4*)base)[0];
  float4 m1 = ((const float4*)base)[1];
  for (int ss = 1; ss < 8; ++ss) {
    const float4* p = (const float4*)(base + (size_t)ss * 2048);
    float4 a = p[0], b = p[1];
    m0.x = fmaxf(m0.x, a.x); m0.y = fmaxf(m0.y, a.y);
    m0.z = fmaxf(m0.z, a.z); m0.w = fmaxf(m0.w, a.w);
    m1.x = fmaxf(m1.x, b.x); m1.y = fmaxf(m1.y, b.y);
    m1.z = fmaxf(m1.z, b.z); m1.w = fmaxf(m1.w, b.w);
  }
  float4* o = (float4*)(partial + ((size_t)(bx * 32 + sg)) * 2048 + t * 8);
  o[0] = m0; o[1] = m1;
}

// reduce2: out[b][l] = max(-1, max over 32 partials)
__global__ void __launch_bounds__(256) reduce2_kernel(
    const float* __restrict__ partial, float* __restrict__ out) {
  int idx = blockIdx.x * 256 + threadIdx.x;   // 0 .. 26623
  if (idx >= 13 * 2048) return;
  int bx = idx >> 11;
  int e  = idx & 2047;
  int b  = e >> 4;
  int ll = e & 15;
  int l  = bx * 16 + ll;
  if (l >= 200) return;
  float m = -1.0f;
  const float* p = partial + (size_t)(bx * 32) * 2048 + e;
  for (int c = 0; c < 32; ++c) m = fmaxf(m, p[(size_t)c * 2048]);
  out[b * 200 + l] = m;
}

// Brute-force fp32 fallback (only if ws_size is too small): one block per (b,l).
__global__ void __launch_bounds__(256) fallback_kernel(
    const float* __restrict__ embed, const float* __restrict__ label,
    float* __restrict__ out) {
  int b = blockIdx.x, l = blockIdx.y, t = threadIdx.x;
  float m = -1.0f;
  for (int p = t; p < 2048; p += 256) {
    int s = p >> 3, v = p & 7;
    const float* e = embed + (size_t)(s * 128 + b) * 768;
    const float* q = label + (size_t)(l * 8 + v) * 768;
    float dot = 0.f, ne = 0.f, nl = 0.f;
    for (int d = 0; d < 768; ++d) {
      float x = e[d], y = q[d];
      dot += x * y; ne += x * x; nl += y * y;
    }
    m = fmaxf(m, dot / fmaxf(sqrtf(ne) * sqrtf(nl), 1e-8f));
  }
  for (int off = 1; off < 64; off <<= 1) m = fmaxf(m, __shfl_xor(m, off));
  __shared__ float wmax[4];
  if ((t & 63) == 0) wmax[t >> 6] = m;
  __syncthreads();
  if (t == 0)
    out[b * 200 + l] = fmaxf(fmaxf(wmax[0], wmax[1]), fmaxf(wmax[2], wmax[3]));
}

extern "C" void kernel_launch(void* const* d_in, const int* in_sizes, int n_in,
                              void* d_out, int out_size, void* d_ws, size_t ws_size,
                              hipStream_t stream) {
  const float* embed = (const float*)d_in[0];   // [256,128,768]
  const float* label = (const float*)d_in[1];   // [200,8,768]
  float* out = (float*)d_out;                   // [128,200]

  const size_t szA = (size_t)32768 * 768 * 2;        // 50,331,648
  const size_t szB = (size_t)1664 * 768 * 2;         //  2,555,904
  const size_t szS = (size_t)13 * 256 * 2048 * 4;    // 27,262,976
  const size_t szP = (size_t)13 * 32 * 2048 * 4;     //  3,407,872

  if (ws_size < szA + szB + szS + szP) {
    dim3 g(128, 200);
    fallback_kernel<<<g, 256, 0, stream>>>(embed, label, out);
    return;
  }

  unsigned short* Ap = (unsigned short*)d_ws;
  unsigned short* Bp = (unsigned short*)((char*)d_ws + szA);
  float* scratch     = (float*)((char*)d_ws + szA + szB);
  float* partial     = (float*)((char*)d_ws + szA + szB + szS);

  normalize_all<<<8608, 256, 0, stream>>>(embed, label, Ap, Bp);
  gemm_store_kernel<<<3328, 256, 0, stream>>>(Ap, Bp, scratch);
  dim3 r1(13, 32);
  reduce1_kernel<<<r1, 256, 0, stream>>>(scratch, partial);
  reduce2_kernel<<<104, 256, 0, stream>>>(partial, out);
}